// Round 9
// baseline (1366.631 us; speedup 1.0000x reference)
//
#include <hip/hip_runtime.h>
#include <cmath>

// Shapes: B=128, D=192, DEPTH=12, H=3(hd=64), E=4, N=65(tokens), NC=100, WIN_HALF=3
#define ROWS 8320
#define DD   192

typedef __attribute__((ext_vector_type(8))) _Float16 half8;
typedef __attribute__((ext_vector_type(4))) float floatx4;

#define GLD16(gp, lp) __builtin_amdgcn_global_load_lds( \
    (const __attribute__((address_space(1))) void*)(gp), \
    (__attribute__((address_space(3))) void*)(lp), 16, 0, 0)

#define MFMA_F16 __builtin_amdgcn_mfma_f32_16x16x32_f16

__device__ __forceinline__ float gelu_f(float x) {
    return 0.5f * x * (1.0f + erff(x * 0.70710678118654752440f));
}

// block-wide sum for blockDim.x == 192 (embed only)
__device__ __forceinline__ float blk_sum_192(float v, float* sbuf) {
    int tid = threadIdx.x;
    sbuf[tid] = v;
    __syncthreads();
    for (int off = 96; off >= 3; off >>= 1) {
        if (tid < off) sbuf[tid] += sbuf[tid + off];
        __syncthreads();
    }
    float r = sbuf[0] + sbuf[1] + sbuf[2];
    __syncthreads();
    return r;
}

// ---------------- flat fp32 -> fp16 ----------------
__global__ __launch_bounds__(256) void cvt_h_kernel(
    const float* __restrict__ s, _Float16* __restrict__ d, long n8)
{
    long i = (long)blockIdx.x * 256 + threadIdx.x;
    if (i >= n8) return;
    const float* sp = s + i * 8;
    _Float16* dp = d + i * 8;
    #pragma unroll
    for (int j = 0; j < 8; j++) dp[j] = (_Float16)sp[j];
}

// e_w2 (12,4,192,384) -> fp16 cat layout [l][n][K'=1536] with col = e*384+k
__global__ __launch_bounds__(256) void permw2h_kernel(
    const float* __restrict__ s, _Float16* __restrict__ d)
{
    long i = (long)blockIdx.x * 256 + threadIdx.x;   // (l, n, p), p in 0..191
    if (i >= (long)12 * 192 * 192) return;
    int l = (int)(i / (192 * 192));
    int rem = (int)(i % (192 * 192));
    int n = rem / 192, p = rem % 192;
    int c0 = p * 8;
    int e = c0 / 384, k0 = c0 % 384;
    const float* sp = s + (((size_t)l * 4 + e) * 192 + n) * 384 + k0;
    _Float16* dp = d + i * 8;
    #pragma unroll
    for (int j = 0; j < 8; j++) dp[j] = (_Float16)sp[j];
}

// ---------------- patch embed + LN + cls + pos (fp32) ----------------
__global__ __launch_bounds__(192) void embed_kernel(
    const float* __restrict__ x, const float* __restrict__ conv_w,
    const float* __restrict__ conv_b, const float* __restrict__ pe_g,
    const float* __restrict__ pe_b, const float* __restrict__ cls_tok,
    const float* __restrict__ pos, float* __restrict__ t)
{
    __shared__ float patch[48];
    __shared__ float red[192];
    int blk = blockIdx.x;
    int b = blk / 65, n = blk % 65;
    int tid = threadIdx.x;
    if (n == 0) {
        t[(size_t)b * 65 * DD + tid] = cls_tok[tid] + pos[tid];
        return;
    }
    int p = n - 1, gy = p / 8, gx = p % 8;
    if (tid < 48) {
        int c = tid / 16, iy = (tid % 16) / 4, ix = tid % 4;
        patch[tid] = x[((size_t)b * 3 + c) * 1024 + (size_t)(gy * 4 + iy) * 32 + (gx * 4 + ix)];
    }
    __syncthreads();
    float s = conv_b[tid];
    const float* w = conv_w + (size_t)tid * 48;
    #pragma unroll
    for (int f = 0; f < 48; f++) s += patch[f] * w[f];
    float mean = blk_sum_192(s, red) * (1.0f / 192.0f);
    float d = s - mean;
    float var = blk_sum_192(d * d, red) * (1.0f / 192.0f);
    float o = d * rsqrtf(var + 1e-5f) * pe_g[tid] + pe_b[tid];
    t[((size_t)b * 65 + n) * DD + tid] = o + pos[(size_t)n * DD + tid];
}

// ---------------- LayerNorm, wave-per-row (4 rows/block, shuffle-only) ----------------
// optional: fold MoE contribs ctb[row][2][192] into the input (and write t back via tout)
// outputs (each optional): yf fp32, yh fp16
// fused gate: softmax(y@gwm^T+gb) top2 -> gwout int4 {e0,e1,bits(w0),bits(w1)}
__global__ __launch_bounds__(256) void ln_kernel(
    const float* __restrict__ in, const float* __restrict__ ctb,
    float* __restrict__ tout,
    float* __restrict__ yf, _Float16* __restrict__ yh,
    const float* __restrict__ g, const float* __restrict__ bb, long in_stride, int nrows,
    const float* __restrict__ gwm, const float* __restrict__ gb,
    int4* __restrict__ gwout)
{
    int wave = threadIdx.x >> 6, lane = threadIdx.x & 63;
    int r = blockIdx.x * 4 + wave;
    if (r >= nrows) return;
    const float* row = in + (size_t)r * in_stride;
    float v0 = row[lane], v1 = row[lane + 64], v2 = row[lane + 128];
    if (ctb) {
        long gr = (long)r * (in_stride / DD);
        const float* cb = ctb + gr * 384;
        v0 += cb[lane] + cb[192 + lane];
        v1 += cb[lane + 64] + cb[256 + lane];
        v2 += cb[lane + 128] + cb[320 + lane];
        if (tout) {
            float* tr = tout + (size_t)r * in_stride;
            tr[lane] = v0; tr[lane + 64] = v1; tr[lane + 128] = v2;
        }
    }
    float s = v0 + v1 + v2;
    #pragma unroll
    for (int off = 32; off > 0; off >>= 1) s += __shfl_xor(s, off);
    float mean = s * (1.0f / 192.0f);
    float d0 = v0 - mean, d1 = v1 - mean, d2 = v2 - mean;
    float q = d0 * d0 + d1 * d1 + d2 * d2;
    #pragma unroll
    for (int off = 32; off > 0; off >>= 1) q += __shfl_xor(q, off);
    float rstd = rsqrtf(q * (1.0f / 192.0f) + 1e-5f);
    float o0 = d0 * rstd * g[lane] + bb[lane];
    float o1 = d1 * rstd * g[lane + 64] + bb[lane + 64];
    float o2 = d2 * rstd * g[lane + 128] + bb[lane + 128];
    if (yf) {
        float* yr = yf + (size_t)r * DD;
        yr[lane] = o0; yr[lane + 64] = o1; yr[lane + 128] = o2;
    }
    if (yh) {
        _Float16* yr = yh + (size_t)r * DD;
        yr[lane] = (_Float16)o0; yr[lane + 64] = (_Float16)o1; yr[lane + 128] = (_Float16)o2;
    }
    if (gwm) {
        float pe[4];
        #pragma unroll
        for (int e = 0; e < 4; e++) {
            const float* w = gwm + (size_t)e * DD;
            pe[e] = o0 * w[lane] + o1 * w[lane + 64] + o2 * w[lane + 128];
            #pragma unroll
            for (int off = 32; off > 0; off >>= 1) pe[e] += __shfl_xor(pe[e], off);
        }
        if (lane == 0) {
            #pragma unroll
            for (int e = 0; e < 4; e++) pe[e] += gb[e];
            float mx = fmaxf(fmaxf(pe[0], pe[1]), fmaxf(pe[2], pe[3]));
            float ex[4];
            #pragma unroll
            for (int e = 0; e < 4; e++) ex[e] = expf(pe[e] - mx);
            int i0 = 0;
            #pragma unroll
            for (int e = 1; e < 4; e++) if (ex[e] > ex[i0]) i0 = e;
            int i1 = (i0 == 0) ? 1 : 0;
            #pragma unroll
            for (int e = 0; e < 4; e++) if (e != i0 && ex[e] > ex[i1]) i1 = e;
            float denom = ex[i0] + ex[i1];
            int4 o4;
            o4.x = i0; o4.y = i1;
            o4.z = __float_as_int(ex[i0] / denom);
            o4.w = __float_as_int(ex[i1] / denom);
            gwout[r] = o4;
        }
    }
}

// ---------------- build per-expert row lists; entry = (row<<1)|rank ----------------
__global__ __launch_bounds__(256) void gate_build_kernel(
    const int4* __restrict__ gwrow, int* __restrict__ cnt,
    int* __restrict__ list, float* __restrict__ wlist, int rows)
{
    int r = blockIdx.x * 256 + threadIdx.x;
    int lane = threadIdx.x & 63;
    bool active = r < rows;
    int4 gv = active ? gwrow[r] : int4{-1, -1, 0, 0};
    #pragma unroll
    for (int e = 0; e < 4; e++) {
        bool sel = active && (gv.x == e || gv.y == e);
        int rank = (gv.x == e) ? 0 : 1;
        float w = (gv.x == e) ? __int_as_float(gv.z) : __int_as_float(gv.w);
        unsigned long long mask = __ballot(sel);
        int cw = __popcll(mask);
        if (cw) {
            int leader = __ffsll((long long)mask) - 1;
            int base = 0;
            if (lane == leader) base = atomicAdd(&cnt[e], cw);
            base = __shfl(base, leader);
            if (sel) {
                int idx = base + __popcll(mask & ((1ULL << lane) - 1ULL));
                list[(size_t)e * ROWS + idx] = (r << 1) | rank;
                wlist[(size_t)e * ROWS + idx] = w;
            }
        }
    }
}

// ---------------- fp16 MFMA GEMM, K=192: C[M,N] = A[M,192] @ W[N,192]^T ----------------
// MODE 0: out fp16 packed [M][Nn]   (qkv; no bias)
// MODE 2: t[r*192+n] += scale[0]*(acc + bias[n])   (proj)
template <int MODE>
__global__ __launch_bounds__(256) void gemm_h(
    const _Float16* __restrict__ A, const _Float16* __restrict__ W,
    int Nn, _Float16* __restrict__ outH, float* __restrict__ t,
    const float* __restrict__ bias, const float* __restrict__ scale)
{
    __shared__ __align__(16) _Float16 As[64 * 192];   // 24KB
    __shared__ __align__(16) _Float16 Ws[64 * 192];   // 24KB
    const int tid = threadIdx.x;
    const int lane = tid & 63, wave = tid >> 6;
    const int m0 = blockIdx.x * 64, n0 = blockIdx.y * 64;
    const int wm = (wave & 1) * 32, wn = (wave >> 1) * 32;
    const int lr = lane & 15, quad = lane >> 4;

    #pragma unroll
    for (int i = 0; i < 6; i++) {
        int s = (wave * 6 + i) * 64 + lane;
        int rr = s / 24, c = s % 24;
        GLD16(A + (size_t)(m0 + rr) * 192 + (c ^ (rr & 7)) * 8,
              (char*)As + (size_t)(wave * 6 + i) * 1024);
        GLD16(W + (size_t)(n0 + rr) * 192 + (c ^ (rr & 7)) * 8,
              (char*)Ws + (size_t)(wave * 6 + i) * 1024);
    }
    __syncthreads();

    floatx4 zero = {0.f, 0.f, 0.f, 0.f};
    floatx4 acc[2][2];
    acc[0][0] = zero; acc[0][1] = zero; acc[1][0] = zero; acc[1][1] = zero;

    #pragma unroll
    for (int m = 0; m < 6; m++) {
        int ch = m * 4 + quad;
        half8 a[2], w[2];
        #pragma unroll
        for (int ti = 0; ti < 2; ti++) {
            int ar = wm + ti * 16 + lr;
            a[ti] = *(const half8*)(As + ((size_t)ar * 24 + (ch ^ (ar & 7))) * 8);
            int cr = wn + ti * 16 + lr;
            w[ti] = *(const half8*)(Ws + ((size_t)cr * 24 + (ch ^ (cr & 7))) * 8);
        }
        #pragma unroll
        for (int ti = 0; ti < 2; ti++)
            #pragma unroll
            for (int tj = 0; tj < 2; tj++)
                acc[ti][tj] = MFMA_F16(a[ti], w[tj], acc[ti][tj], 0, 0, 0);
    }

    float sc = (MODE == 2) ? scale[0] : 0.f;
    #pragma unroll
    for (int ti = 0; ti < 2; ti++)
        #pragma unroll
        for (int tj = 0; tj < 2; tj++)
            #pragma unroll
            for (int r = 0; r < 4; r++) {
                int grow = m0 + wm + ti * 16 + quad * 4 + r;
                int gcol = n0 + wn + tj * 16 + lr;
                float v = acc[ti][tj][r];
                if (MODE == 0) {
                    float vp = __shfl_xor(v, 1);
                    if ((lane & 1) == 0) {
                        union { _Float16 h[2]; unsigned u; } pk;
                        pk.h[0] = (_Float16)v;
                        pk.h[1] = (_Float16)vp;
                        *(unsigned*)(outH + (size_t)grow * Nn + (gcol & ~1)) = pk.u;
                    }
                } else {
                    t[(size_t)grow * DD + gcol] += sc * (v + bias[gcol]);
                }
            }
}

// ---------------- fused MoE v4: software-pipelined single-barrier loop ----------------
// grid (260, 4): block = 32 gathered rows of expert e; 12 bodies of 32 h-cols.
// Per body: issue W1[nc+1] & W2[nc] (double-buffered), gemm1(nc), gelu->Hs[p],
// gemm2(nc-1) from previous buffers, ONE barrier. Loads get a full body of cover.
// ctb[row][rank][192] = mlp_sc * w * (gelu(y@w1_e^T+b1_e)@w2_e^T + b2_e)
__global__ __launch_bounds__(256) void moe_kernel(
    const _Float16* __restrict__ yh, const _Float16* __restrict__ w1,
    const _Float16* __restrict__ w2, const float* __restrict__ b1,
    const float* __restrict__ b2, const float* __restrict__ scale,
    const int* __restrict__ cnt, const int* __restrict__ list,
    const float* __restrict__ wlist, float* __restrict__ ctb)
{
    __shared__ __align__(16) _Float16 As[32 * 192];      // 12KB
    __shared__ __align__(16) _Float16 W1s[2][32 * 192];  // 2x12KB
    __shared__ __align__(16) _Float16 W2s[2][192 * 32];  // 2x12KB
    __shared__ __align__(16) _Float16 Hs[2][32 * 32];    // 2x2KB
    __shared__ int   rl[32];
    __shared__ int   rk[32];
    __shared__ float wl[32];
    const int e  = blockIdx.y;
    const int cnte = cnt[e];
    const int r0 = blockIdx.x * 32;
    if (r0 >= cnte) return;
    const int tid = threadIdx.x;
    const int lane = tid & 63, wave = tid >> 6;
    const int lr = lane & 15, quad = lane >> 4;
    const int wr  = (wave & 1) * 16;      // rows (both gemms)
    const int wc1 = (wave >> 1) * 16;     // gemm1 hcol base (of 32)
    const int wc2 = (wave >> 1) * 96;     // gemm2 col base (of 192)

    if (tid < 32) {
        int sl = r0 + tid;
        bool ok = sl < cnte;
        int v = ok ? list[(size_t)e * ROWS + sl] : 0;
        rl[tid] = v >> 1;
        rk[tid] = ok ? (v & 1) : -1;
        wl[tid] = ok ? wlist[(size_t)e * ROWS + sl] : 0.f;
    }
    __syncthreads();

    // As: 32 gathered rows x 24 chunks (768 slots, 3/thread)
    #pragma unroll
    for (int i = 0; i < 3; i++) {
        int s = (wave * 3 + i) * 64 + lane;
        int rr = s / 24, c = s % 24;
        GLD16(yh + (size_t)rl[rr] * 192 + (c ^ (rr & 7)) * 8, (char*)As + s * 16);
    }
    // W1[0] -> W1s[0]
    #pragma unroll
    for (int i = 0; i < 3; i++) {
        int s = (wave * 3 + i) * 64 + lane;
        int rr = s / 24, c = s % 24;
        GLD16(w1 + ((size_t)e * 384 + rr) * 192 + (c ^ (rr & 7)) * 8,
              (char*)W1s[0] + s * 16);
    }
    __syncthreads();

    floatx4 zero = {0.f, 0.f, 0.f, 0.f};
    floatx4 acc2[6];
    #pragma unroll
    for (int j = 0; j < 6; j++) acc2[j] = zero;
    const float sc = scale[0];

    #pragma unroll
    for (int nc = 0; nc < 12; nc++) {
        const int p = nc & 1;
        const int ncg = e * 12 + nc;
        // (1) issue W1[nc+1] -> W1s[1-p]  (read next body; last read of [1-p] was body nc-1)
        if (nc < 11) {
            #pragma unroll
            for (int i = 0; i < 3; i++) {
                int s = (wave * 3 + i) * 64 + lane;
                int rr = s / 24, c = s % 24;
                GLD16(w1 + ((size_t)e * 384 + (nc + 1) * 32 + rr) * 192 + (c ^ (rr & 7)) * 8,
                      (char*)W1s[1 - p] + s * 16);
            }
        }
        // (2) issue W2[nc] -> W2s[p]  (read next body by gemm2(nc); last read was body nc-1)
        #pragma unroll
        for (int i = 0; i < 3; i++) {
            int s = (wave * 3 + i) * 64 + lane;
            int n = s >> 2, c = s & 3;
            GLD16(w2 + (size_t)n * 1536 + ((size_t)ncg * 4 + (c ^ ((n >> 2) & 3))) * 8,
                  (char*)W2s[p] + s * 16);
        }
        // (3) gemm1(nc): rows wr..+16 x hcols wc1..+16, K=192 (W1s[p] loaded last body)
        floatx4 acc1 = zero;
        #pragma unroll
        for (int m = 0; m < 6; m++) {
            int ch = m * 4 + quad;
            int ar = wr + lr;
            half8 a = *(const half8*)(As + ((size_t)ar * 24 + (ch ^ (ar & 7))) * 8);
            int cr = wc1 + lr;
            half8 w = *(const half8*)(W1s[p] + ((size_t)cr * 24 + (ch ^ (cr & 7))) * 8);
            acc1 = MFMA_F16(a, w, acc1, 0, 0, 0);
        }
        // (4) epilogue: gelu*gate -> Hs[p] (packed 32-bit, (row>>2)&3 chunk swizzle)
        #pragma unroll
        for (int r = 0; r < 4; r++) {
            int hrow = wr + quad * 4 + r;
            int hcol = wc1 + lr;
            float v = gelu_f(acc1[r] + b1[32 * ncg + hcol]) * wl[hrow];
            float vp = __shfl_xor(v, 1);
            if ((lane & 1) == 0) {
                union { _Float16 h[2]; unsigned u; } pk;
                pk.h[0] = (_Float16)v;
                pk.h[1] = (_Float16)vp;
                int cl = (hcol >> 3) ^ ((hrow >> 2) & 3);
                *(unsigned*)(Hs[p] + ((size_t)hrow * 4 + cl) * 8 + (hcol & 6)) = pk.u;
            }
        }
        // (5) gemm2(nc-1): K=32, A=Hs[1-p] (written last body), B=W2s[1-p]
        if (nc > 0) {
            int ar = wr + lr;
            half8 a = *(const half8*)(Hs[1 - p] + ((size_t)ar * 4 + (quad ^ ((ar >> 2) & 3))) * 8);
            #pragma unroll
            for (int tj = 0; tj < 6; tj++) {
                int cr = wc2 + tj * 16 + lr;
                half8 w = *(const half8*)(W2s[1 - p] + ((size_t)cr * 4 + (quad ^ ((cr >> 2) & 3))) * 8);
                acc2[tj] = MFMA_F16(a, w, acc2[tj], 0, 0, 0);
            }
        }
        // (6) one barrier: drains (1)+(2) [full-body cover], publishes Hs[p]
        __syncthreads();
    }
    // final gemm2(11): nc=11 had p=1 -> Hs[1], W2s[1]
    {
        int ar = wr + lr;
        half8 a = *(const half8*)(Hs[1] + ((size_t)ar * 4 + (quad ^ ((ar >> 2) & 3))) * 8);
        #pragma unroll
        for (int tj = 0; tj < 6; tj++) {
            int cr = wc2 + tj * 16 + lr;
            half8 w = *(const half8*)(W2s[1] + ((size_t)cr * 4 + (quad ^ ((cr >> 2) & 3))) * 8);
            acc2[tj] = MFMA_F16(a, w, acc2[tj], 0, 0, 0);
        }
    }

    #pragma unroll
    for (int tj = 0; tj < 6; tj++) {
        int gcol = wc2 + tj * 16 + lr;
        #pragma unroll
        for (int r = 0; r < 4; r++) {
            int lrow = wr + quad * 4 + r;
            int rank = rk[lrow];
            if (rank >= 0) {
                float v = sc * (acc2[tj][r] + wl[lrow] * b2[e * 192 + gcol]);
                ctb[((size_t)rl[lrow] * 2 + rank) * 192 + gcol] = v;
            }
        }
    }
}

// ---------------- banded attention: fp16 in/out, fp32 compute ----------------
__global__ __launch_bounds__(256) void attn_kernel(
    const _Float16* __restrict__ qkv, const float* __restrict__ temp,
    _Float16* __restrict__ o)
{
    __shared__ float q[65][64], k[65][64], v[65][64];
    __shared__ float p[65][8];
    int bh = blockIdx.x;
    int b = bh / 3, h = bh % 3;
    int tid = threadIdx.x;
    float coef = 0.125f / temp[h];
    const _Float16* base = qkv + (size_t)b * 65 * 576 + h * 64;
    for (int idx = tid; idx < 65 * 64; idx += 256) {
        int i = idx >> 6, d = idx & 63;
        q[i][d] = (float)base[(size_t)i * 576 + d];
        k[i][d] = (float)base[(size_t)i * 576 + 192 + d];
        v[i][d] = (float)base[(size_t)i * 576 + 384 + d];
    }
    __syncthreads();
    if (tid < 65) {
        int i = tid;
        float sc[7];
        float mx = -1e30f;
        #pragma unroll
        for (int jo = 0; jo < 7; jo++) {
            int j = i - 3 + jo;
            if (j >= 0 && j < 65) {
                float s = 0.f;
                #pragma unroll
                for (int d = 0; d < 64; d++) s += q[i][d] * k[j][d];
                sc[jo] = s * coef;
                mx = fmaxf(mx, sc[jo]);
            } else sc[jo] = -1e30f;
        }
        float sum = 0.f;
        #pragma unroll
        for (int jo = 0; jo < 7; jo++) {
            float e = expf(sc[jo] - mx);
            p[i][jo] = e;
            sum += e;
        }
        float inv = 1.0f / sum;
        #pragma unroll
        for (int jo = 0; jo < 7; jo++) p[i][jo] *= inv;
    }
    __syncthreads();
    for (int idx = tid; idx < 65 * 64; idx += 256) {
        int i = idx >> 6, d = idx & 63;
        float s = 0.f;
        #pragma unroll
        for (int jo = 0; jo < 7; jo++) {
            int j = i - 3 + jo;
            if (j >= 0 && j < 65) s += p[i][jo] * v[j][d];
        }
        o[((size_t)b * 65 + i) * 192 + h * 64 + d] = (_Float16)s;
    }
}

// ---------------- hyper head (fp32) ----------------
__global__ __launch_bounds__(128) void head_kernel(
    const float* __restrict__ cls, const float* __restrict__ hc_w,
    const float* __restrict__ hc_b, const float* __restrict__ head_w,
    const float* __restrict__ head_b, float* __restrict__ out)
{
    __shared__ float c[192];
    __shared__ float hh[384];
    int b = blockIdx.x, tid = threadIdx.x;
    for (int i = tid; i < 192; i += 128) c[i] = cls[(size_t)b * 192 + i];
    __syncthreads();
    for (int i = tid; i < 384; i += 128) {
        int k = i / 96, o = i % 96;
        float s = hc_b[i];
        #pragma unroll
        for (int j = 0; j < 4; j++) {
            int pp = (k - j + 4) & 3;
            const float* w = hc_w + ((size_t)pp * 96 + o) * 48;
            const float* xv = c + j * 48;
            #pragma unroll
            for (int cc = 0; cc < 48; cc++) s += xv[cc] * w[cc];
        }
        hh[i] = gelu_f(s);
    }
    __syncthreads();
    for (int i = tid; i < 100; i += 128) {
        float s = head_b[i];
        const float* w = head_w + (size_t)i * 384;
        for (int kk = 0; kk < 384; kk++) s += hh[kk] * w[kk];
        out[(size_t)b * 100 + i] = s;
    }
}

extern "C" void kernel_launch(void* const* d_in, const int* in_sizes, int n_in,
                              void* d_out, int out_size, void* d_ws, size_t ws_size,
                              hipStream_t stream)
{
    const float* x        = (const float*)d_in[0];
    const float* conv_w   = (const float*)d_in[1];
    const float* conv_b   = (const float*)d_in[2];
    const float* pe_g     = (const float*)d_in[3];
    const float* pe_b     = (const float*)d_in[4];
    const float* cls_tok  = (const float*)d_in[5];
    const float* pos      = (const float*)d_in[6];
    const float* n1_g     = (const float*)d_in[7];
    const float* n1_b     = (const float*)d_in[8];
    const float* qkv_w    = (const float*)d_in[9];
    const float* temp     = (const float*)d_in[10];
    const float* proj_w   = (const float*)d_in[11];
    const float* proj_b   = (const float*)d_in[12];
    const float* n2_g     = (const float*)d_in[13];
    const float* n2_b     = (const float*)d_in[14];
    const float* gate_w   = (const float*)d_in[15];
    const float* gate_b   = (const float*)d_in[16];
    const float* e_w1     = (const float*)d_in[17];
    const float* e_b1     = (const float*)d_in[18];
    const float* e_w2     = (const float*)d_in[19];
    const float* e_b2     = (const float*)d_in[20];
    const float* attn_sc  = (const float*)d_in[21];
    const float* mlp_sc   = (const float*)d_in[22];
    const float* norm_g   = (const float*)d_in[23];
    const float* norm_b   = (const float*)d_in[24];
    const float* hc_w     = (const float*)d_in[25];
    const float* hc_b     = (const float*)d_in[26];
    const float* head_w   = (const float*)d_in[27];
    const float* head_b   = (const float*)d_in[28];

    // ---- ws layout ----
    char* base = (char*)d_ws;
    float*  t     = (float*)base;   base += (size_t)ROWS * DD * 4;        // 6.39MB
    float*  ctb   = (float*)base;   base += (size_t)ROWS * 384 * 4;       // 12.8MB
    int4*   gwrow = (int4*)base;    base += (size_t)ROWS * 16;            // 133KB
    int*    cnts  = (int*)base;     base += (size_t)12 * 4 * sizeof(int) + 64;
    int*    elist = (int*)base;     base += (size_t)4 * ROWS * 4;         // 133KB
    float*  ewls  = (float*)base;   base += (size_t)4 * ROWS * 4;         // 133KB
    float*  ycls  = (float*)base;   base += (size_t)128 * DD * 4;         // 98KB
    _Float16* yhb = (_Float16*)base; base += (size_t)ROWS * DD * 2;       // 3.19MB
    _Float16* qkvh = (_Float16*)base; base += (size_t)ROWS * 576 * 2;     // 9.58MB
    _Float16* osph = (_Float16*)base; base += (size_t)ROWS * DD * 2;      // 3.19MB
    _Float16* qkvw_h = (_Float16*)base; base += (size_t)12 * 576 * 192 * 2;  // 2.65MB
    _Float16* projw_h = (_Float16*)base; base += (size_t)12 * 192 * 192 * 2; // 0.88MB
    _Float16* ew1_h = (_Float16*)base; base += (size_t)12 * 1536 * 192 * 2;  // 7.1MB
    _Float16* ew2_h = (_Float16*)base; base += (size_t)12 * 192 * 1536 * 2;  // 7.1MB

    hipMemsetAsync(cnts, 0, 12 * 4 * sizeof(int), stream);

    // ---- weight conversion ----
    {
        long n8 = (long)12 * 576 * 192 / 8;
        cvt_h_kernel<<<(int)((n8 + 255) / 256), 256, 0, stream>>>(qkv_w, qkvw_h, n8);
        n8 = (long)12 * 192 * 192 / 8;
        cvt_h_kernel<<<(int)((n8 + 255) / 256), 256, 0, stream>>>(proj_w, projw_h, n8);
        n8 = (long)12 * 1536 * 192 / 8;
        cvt_h_kernel<<<(int)((n8 + 255) / 256), 256, 0, stream>>>(e_w1, ew1_h, n8);
        long n = (long)12 * 192 * 192;
        permw2h_kernel<<<(int)((n + 255) / 256), 256, 0, stream>>>(e_w2, ew2_h);
    }

    embed_kernel<<<128 * 65, 192, 0, stream>>>(x, conv_w, conv_b, pe_g, pe_b, cls_tok, pos, t);

    for (int l = 0; l < 12; l++) {
        // ln1: fold previous layer's MoE contribs into t (l>0), emit fp16 y
        ln_kernel<<<ROWS / 4, 256, 0, stream>>>(
            t, (l > 0) ? ctb : nullptr, (l > 0) ? t : nullptr,
            nullptr, yhb, n1_g + l * DD, n1_b + l * DD, DD, ROWS,
            nullptr, nullptr, nullptr);
        gemm_h<0><<<dim3(130, 9), 256, 0, stream>>>(
            yhb, qkvw_h + (size_t)l * 576 * 192, 576, qkvh, nullptr, nullptr, nullptr);
        attn_kernel<<<128 * 3, 256, 0, stream>>>(qkvh, temp + l * 3, osph);
        gemm_h<2><<<dim3(130, 3), 256, 0, stream>>>(
            osph, projw_h + (size_t)l * 192 * 192, 192, nullptr, t,
            proj_b + l * DD, attn_sc + l);
        // ln2 + gate
        ln_kernel<<<ROWS / 4, 256, 0, stream>>>(
            t, nullptr, nullptr, nullptr, yhb, n2_g + l * DD, n2_b + l * DD, DD, ROWS,
            gate_w + (size_t)l * 4 * DD, gate_b + l * 4, gwrow);
        gate_build_kernel<<<(ROWS + 255) / 256, 256, 0, stream>>>(
            gwrow, cnts + l * 4, elist, ewls, ROWS);
        moe_kernel<<<dim3(260, 4), 256, 0, stream>>>(
            yhb, ew1_h + (size_t)l * 1536 * 192, ew2_h + (size_t)l * 192 * 1536,
            e_b1 + (size_t)l * 1536, e_b2 + (size_t)l * 4 * 192, mlp_sc + l,
            cnts + l * 4, elist, ewls, ctb);
    }

    // final LN on cls rows: fold last MoE contribs (stride-aware)
    ln_kernel<<<32, 256, 0, stream>>>(
        t, ctb, nullptr, ycls, nullptr, norm_g, norm_b, (long)65 * DD, 128,
        nullptr, nullptr, nullptr);
    head_kernel<<<128, 128, 0, stream>>>(ycls, hc_w, hc_b, head_w, head_b, (float*)d_out);
}